// Round 1
// baseline (2065.298 us; speedup 1.0000x reference)
//
#include <hip/hip_runtime.h>

// spiking coESN: B=2048 independent samples, L=1024 steps, N_HID=1024.
// One block per sample, 256 threads, thread t owns hidden units 4t..4t+3.
// Recurrent s@h2h handled as ballot-bitmask sparse row gather (s is binary,
// expected spike rate ~0). One __syncthreads per timestep via double-buffered
// spike masks in LDS. Deterministic accumulation order (graph replay revalidates).

#define NH 1024
#define LT 1024

__global__ __launch_bounds__(256, 4)
void coesn_kernel(const float* __restrict__ x,      // (B, L, 1)
                  const float* __restrict__ x2h,    // (1, NH)
                  const float* __restrict__ h2h,    // (NH, NH) row-major
                  const float* __restrict__ bias,   // (NH,)
                  const float* __restrict__ gam,    // (NH,)
                  const float* __restrict__ eps,    // (NH,)
                  const float* __restrict__ sgain,  // (1,)
                  float* __restrict__ out)          // (B, 2*NH)
{
    const int b    = blockIdx.x;
    const int tid  = threadIdx.x;     // 0..255
    const int lane = tid & 63;
    const int wv   = tid >> 6;        // wave id 0..3

    __shared__ float xrow[LT];                       // this sample's input series
    __shared__ unsigned long long mbuf[2][16];       // [parity][wave*4+u] spike masks

    // Stage x[b,:,0] (1024 contiguous floats) into LDS: 256 threads x float4.
    ((float4*)xrow)[tid] = ((const float4*)(x + (size_t)b * LT))[tid];
    if (tid < 16) mbuf[0][tid] = 0ull;               // step 0: s = 0

    // Per-unit constants, units j = 4t..4t+3 (contiguous -> float4 loads).
    const float sg = sgain[0];
    float g[4], ep[4], bi[4], wx[4];
    {
        float4 t4;
        t4 = ((const float4*)gam)[tid];  g[0]=t4.x;  g[1]=t4.y;  g[2]=t4.z;  g[3]=t4.w;
        t4 = ((const float4*)eps)[tid];  ep[0]=t4.x; ep[1]=t4.y; ep[2]=t4.z; ep[3]=t4.w;
        t4 = ((const float4*)bias)[tid]; bi[0]=t4.x; bi[1]=t4.y; bi[2]=t4.z; bi[3]=t4.w;
        t4 = ((const float4*)x2h)[tid];  wx[0]=t4.x; wx[1]=t4.y; wx[2]=t4.z; wx[3]=t4.w;
    }

    const float dt    = 0.01f;
    const float dec_f = expf(-0.001f);   // exp(-DT/TAU_FILTER)
    const float dec_r = expf(-0.04f);    // exp(-DT/TAU_REF)

    float hy[4] = {0,0,0,0}, hz[4] = {0,0,0,0}, rf[4] = {0,0,0,0};
    float vv[4] = {0,0,0,0}, ft[4] = {0,0,0,0}, fs[4] = {0,0,0,0};

    __syncthreads();

    const float4* h2h4 = (const float4*)h2h;   // row k: h2h4[k*256 + tid]

    for (int step = 0; step < LT; ++step) {
        const int p = step & 1;
        float a[4] = {0.f, 0.f, 0.f, 0.f};

        // Sparse recurrent gather: masks are block-uniform -> no divergence;
        // each set bit = one coalesced 4KB row add (16B/lane).
        #pragma unroll
        for (int w = 0; w < 4; ++w) {
            #pragma unroll
            for (int u = 0; u < 4; ++u) {
                unsigned long long m = mbuf[p][w * 4 + u];
                while (m) {
                    const int l = __builtin_ctzll(m);
                    m &= (m - 1);
                    const int k = (((w << 6) | l) << 2) | u;   // spiking unit index
                    const float4 r = h2h4[(size_t)k * 256 + tid];
                    a[0] += r.x; a[1] += r.y; a[2] += r.z; a[3] += r.w;
                }
            }
        }

        const float xt = xrow[step];
        float sn[4];
        #pragma unroll
        for (int u = 0; u < 4; ++u) {
            const float I = xt * wx[u] + a[u] + bi[u];
            vv[u] += dt * (I - vv[u] * 0.05f);            // -v/LIF_TAU_M + I
            const float ls = (vv[u] > 1.0f) ? 1.0f : 0.0f; // LIF spike
            vv[u] -= ls;                                   // subtract THETA_LIF
            hz[u] += dt * (sg * ls - g[u] * hy[u] - ep[u] * hz[u]);
            hy[u] += dt * hz[u];                           // uses updated hz
            sn[u] = ((hy[u] - 1.0f - rf[u]) > 0.0f) ? 1.0f : 0.0f; // RF spike, old ref
            rf[u] = rf[u] * dec_r + sn[u];
            ft[u] = ft[u] * dec_f + sn[u];
            fs[u] += ft[u];
        }

        // Publish next step's spike masks (double-buffered; 1 barrier/step).
        const unsigned long long m0 = __ballot(sn[0] != 0.0f);
        const unsigned long long m1 = __ballot(sn[1] != 0.0f);
        const unsigned long long m2 = __ballot(sn[2] != 0.0f);
        const unsigned long long m3 = __ballot(sn[3] != 0.0f);
        if (lane == 0) {
            mbuf[p ^ 1][wv * 4 + 0] = m0;
            mbuf[p ^ 1][wv * 4 + 1] = m1;
            mbuf[p ^ 1][wv * 4 + 2] = m2;
            mbuf[p ^ 1][wv * 4 + 3] = m3;
        }
        __syncthreads();
    }

    // out[b] = concat(fts/L, ft)
    const float inv = 1.0f / 1024.0f;   // exact pow2
    float* ob = out + (size_t)b * (2 * NH);
    float4 mo = {fs[0] * inv, fs[1] * inv, fs[2] * inv, fs[3] * inv};
    float4 to = {ft[0], ft[1], ft[2], ft[3]};
    ((float4*)ob)[tid]          = mo;
    ((float4*)(ob + NH))[tid]   = to;
}

extern "C" void kernel_launch(void* const* d_in, const int* in_sizes, int n_in,
                              void* d_out, int out_size, void* d_ws, size_t ws_size,
                              hipStream_t stream) {
    const float* x     = (const float*)d_in[0];
    const float* x2h   = (const float*)d_in[1];
    const float* h2h   = (const float*)d_in[2];
    const float* bias  = (const float*)d_in[3];
    const float* gam   = (const float*)d_in[4];
    const float* eps   = (const float*)d_in[5];
    const float* sgain = (const float*)d_in[6];
    float* out = (float*)d_out;

    coesn_kernel<<<dim3(2048), dim3(256), 0, stream>>>(
        x, x2h, h2h, bias, gam, eps, sgain, out);
}

// Round 2
// 840.088 us; speedup vs baseline: 2.4584x; 2.4584x over previous
//
#include <hip/hip_runtime.h>

// spiking coESN: B=2048 samples, L=1024 steps, N_HID=1024.
// R2: ONE WAVE PER SAMPLE. 256-thread blocks = 4 independent waves = 4 samples.
// Thread lane owns 16 units: unit(j,c) = j*256 + lane*4 + c  (j,c in [0,4)),
// so all global accesses (consts, h2h rows, output) are coalesced float4.
// Spike masks live in SGPRs via __ballot (uniform) -> empty-mask scan is pure
// scalar-pipe work; NO per-step __syncthreads, NO LDS mask traffic. Only LDS
// op per step is one broadcast xt read, software-pipelined one step ahead.
// Pointwise math is expression-identical to the R1 passing kernel (same
// contraction, a[] always added, same gather summation order) => bit-stable
// spike times.

#define NH 1024
#define LT 1024

__global__ __launch_bounds__(256, 2)
void coesn_kernel(const float* __restrict__ x,      // (B, L, 1)
                  const float* __restrict__ x2h,    // (1, NH)
                  const float* __restrict__ h2h,    // (NH, NH) row-major
                  const float* __restrict__ bias,   // (NH,)
                  const float* __restrict__ gam,    // (NH,)
                  const float* __restrict__ eps,    // (NH,)
                  const float* __restrict__ sgain,  // (1,)
                  float* __restrict__ out)          // (B, 2*NH)
{
    const int tid  = threadIdx.x;     // 0..255
    const int lane = tid & 63;
    const int wv   = tid >> 6;        // wave id 0..3 -> sample within block
    const int b    = blockIdx.x * 4 + wv;

    __shared__ float xs[4 * LT];      // 4 samples' input series, 16 KB

    // Stage 16 KB contiguous (4 samples x 1024 floats): 256 thr x float4 x 4.
    {
        const float4* src = (const float4*)(x + (size_t)blockIdx.x * 4 * LT);
        float4* dst = (float4*)xs;
        #pragma unroll
        for (int i = 0; i < 4; ++i)
            dst[tid + 256 * i] = src[tid + 256 * i];
    }

    // Per-unit constants; unit(j,c) = j*256 + lane*4 + c -> float4 idx j*64+lane.
    float g[16], ep[16], bi[16], wx[16];
    #pragma unroll
    for (int j = 0; j < 4; ++j) {
        const int fi = j * 64 + lane;
        float4 t4;
        t4 = ((const float4*)gam)[fi];
        g[j*4+0]=t4.x;  g[j*4+1]=t4.y;  g[j*4+2]=t4.z;  g[j*4+3]=t4.w;
        t4 = ((const float4*)eps)[fi];
        ep[j*4+0]=t4.x; ep[j*4+1]=t4.y; ep[j*4+2]=t4.z; ep[j*4+3]=t4.w;
        t4 = ((const float4*)bias)[fi];
        bi[j*4+0]=t4.x; bi[j*4+1]=t4.y; bi[j*4+2]=t4.z; bi[j*4+3]=t4.w;
        t4 = ((const float4*)x2h)[fi];
        wx[j*4+0]=t4.x; wx[j*4+1]=t4.y; wx[j*4+2]=t4.z; wx[j*4+3]=t4.w;
    }

    const float sg    = sgain[0];
    const float dt    = 0.01f;
    const float dec_f = expf(-0.001f);   // exp(-DT/TAU_FILTER)
    const float dec_r = expf(-0.04f);    // exp(-DT/TAU_REF)

    float hy[16], hz[16], rf[16], vv[16], ft[16], fs[16], a[16];
    unsigned long long msk[16];
    #pragma unroll
    for (int s = 0; s < 16; ++s) {
        hy[s]=0.f; hz[s]=0.f; rf[s]=0.f; vv[s]=0.f; ft[s]=0.f; fs[s]=0.f; a[s]=0.f;
        msk[s]=0ull;
    }

    __syncthreads();

    const float4* h2h4 = (const float4*)h2h;   // row k: h2h4[k*256 + j*64 + lane]
    float xt = xs[wv * LT];                    // step 0 input (broadcast read)

    for (int step = 0; step < LT; ++step) {
        // Software-pipelined next-step input (hides ~120cy LDS latency).
        const float xt_next = xs[wv * LT + ((step + 1) & (LT - 1))];

        // ---- sparse recurrent gather from PREVIOUS step's spikes ----
        // masks are ballot results -> SGPRs; empty check is scalar-pipe only.
        unsigned long long anyp = 0ull;
        #pragma unroll
        for (int s = 0; s < 16; ++s) anyp |= msk[s];
        if (anyp) {
            // Same summation order as R1: (block j, mod c, lane l) ascending.
            #pragma unroll
            for (int s = 0; s < 16; ++s) {
                unsigned long long m = msk[s];
                while (m) {
                    const int l = __builtin_ctzll(m);
                    m &= (m - 1);
                    const int k = (s >> 2) * 256 + l * 4 + (s & 3); // spiked unit
                    const size_t rowb = (size_t)k * 256;
                    #pragma unroll
                    for (int jj = 0; jj < 4; ++jj) {
                        const float4 r = h2h4[rowb + jj * 64 + lane];
                        a[jj*4+0] += r.x; a[jj*4+1] += r.y;
                        a[jj*4+2] += r.z; a[jj*4+3] += r.w;
                    }
                }
            }
        }

        // ---- pointwise update, 16 units (identical expressions to R1) ----
        #pragma unroll
        for (int s = 0; s < 16; ++s) {
            const float I = xt * wx[s] + a[s] + bi[s];
            vv[s] += dt * (I - vv[s] * 0.05f);             // -v/LIF_TAU_M + I
            const float ls = (vv[s] > 1.0f) ? 1.0f : 0.0f; // LIF spike
            vv[s] -= ls;
            hz[s] += dt * (sg * ls - g[s] * hy[s] - ep[s] * hz[s]);
            hy[s] += dt * hz[s];
            const bool sc = (hy[s] - 1.0f - rf[s]) > 0.0f; // RF spike, old ref
            const float sn = sc ? 1.0f : 0.0f;
            msk[s] = __ballot(sc);                         // same cmp -> CSE'd
            rf[s] = rf[s] * dec_r + sn;
            ft[s] = ft[s] * dec_f + sn;
            fs[s] += ft[s];
        }

        if (anyp) {   // uniform: only clear accumulators if they were touched
            #pragma unroll
            for (int s = 0; s < 16; ++s) a[s] = 0.f;
        }
        xt = xt_next;
    }

    // out[b] = concat(fts/L, ft); coalesced float4 stores.
    const float inv = 1.0f / 1024.0f;   // exact pow2
    float* ob = out + (size_t)b * (2 * NH);
    #pragma unroll
    for (int j = 0; j < 4; ++j) {
        float4 mo = {fs[j*4+0]*inv, fs[j*4+1]*inv, fs[j*4+2]*inv, fs[j*4+3]*inv};
        float4 to = {ft[j*4+0], ft[j*4+1], ft[j*4+2], ft[j*4+3]};
        ((float4*)ob)[j*64 + lane]        = mo;
        ((float4*)(ob + NH))[j*64 + lane] = to;
    }
}

extern "C" void kernel_launch(void* const* d_in, const int* in_sizes, int n_in,
                              void* d_out, int out_size, void* d_ws, size_t ws_size,
                              hipStream_t stream) {
    const float* x     = (const float*)d_in[0];
    const float* x2h   = (const float*)d_in[1];
    const float* h2h   = (const float*)d_in[2];
    const float* bias  = (const float*)d_in[3];
    const float* gam   = (const float*)d_in[4];
    const float* eps   = (const float*)d_in[5];
    const float* sgain = (const float*)d_in[6];
    float* out = (float*)d_out;

    coesn_kernel<<<dim3(2048 / 4), dim3(256), 0, stream>>>(
        x, x2h, h2h, bias, gam, eps, sgain, out);
}

// Round 3
// 809.817 us; speedup vs baseline: 2.5503x; 1.0374x over previous
//
#include <hip/hip_runtime.h>

// spiking coESN: B=2048 samples, L=1024 steps, N_HID=1024.
// R3: one wave per sample, 64-thread blocks (wave-private LDS, no block barrier
// in the loop). Lane owns 16 units: unit(j,c) = j*256 + lane*4 + c.
// Hot path is 17 VALU/unit-step: constants pinned into VGPRs via empty asm
// (R2's VGPR_Count=100 showed the allocator rematerializing const loads inside
// the loop), recurrent-input add folded into the (never-taken) spike branch as
// vv += dt*a (exact to O(dt^2), and masks are empty for these inputs anyway).
// Spike masks are ballot results in SGPRs; empty-check is scalar-pipe only.

#define NH 1024
#define LT 1024

__global__ __launch_bounds__(64, 2)   // 2 waves/SIMD resident -> VGPR cap 256
void coesn_kernel(const float* __restrict__ x,      // (B, L, 1)
                  const float* __restrict__ x2h,    // (1, NH)
                  const float* __restrict__ h2h,    // (NH, NH) row-major
                  const float* __restrict__ bias,   // (NH,)
                  const float* __restrict__ gam,    // (NH,)
                  const float* __restrict__ eps,    // (NH,)
                  const float* __restrict__ sgain,  // (1,)
                  float* __restrict__ out)          // (B, 2*NH)
{
    const int lane = threadIdx.x;     // 0..63, one wave per block
    const int b    = blockIdx.x;

    __shared__ float xrow[LT];        // this sample's input series, 4 KB

    // Stage x[b,:,0]: 64 threads x float4 x 4 iters = 1024 floats.
    {
        const float4* src = (const float4*)(x + (size_t)b * LT);
        float4* dst = (float4*)xrow;
        #pragma unroll
        for (int i = 0; i < 4; ++i)
            dst[lane + 64 * i] = src[lane + 64 * i];
    }

    // Per-unit constants; unit(j,c) = j*256 + lane*4 + c -> float4 idx j*64+lane.
    float g[16], ep[16], bi[16], wx[16];
    #pragma unroll
    for (int j = 0; j < 4; ++j) {
        const int fi = j * 64 + lane;
        float4 t4;
        t4 = ((const float4*)gam)[fi];
        g[j*4+0]=t4.x;  g[j*4+1]=t4.y;  g[j*4+2]=t4.z;  g[j*4+3]=t4.w;
        t4 = ((const float4*)eps)[fi];
        ep[j*4+0]=t4.x; ep[j*4+1]=t4.y; ep[j*4+2]=t4.z; ep[j*4+3]=t4.w;
        t4 = ((const float4*)bias)[fi];
        bi[j*4+0]=t4.x; bi[j*4+1]=t4.y; bi[j*4+2]=t4.z; bi[j*4+3]=t4.w;
        t4 = ((const float4*)x2h)[fi];
        wx[j*4+0]=t4.x; wx[j*4+1]=t4.y; wx[j*4+2]=t4.z; wx[j*4+3]=t4.w;
    }
    // Pin constants into VGPRs: block rematerialization/sinking into the loop.
    #pragma unroll
    for (int s = 0; s < 16; ++s) {
        asm volatile("" : "+v"(g[s]), "+v"(ep[s]), "+v"(bi[s]), "+v"(wx[s]));
    }

    const float sg    = sgain[0];
    const float dt    = 0.01f;
    const float dec_f = expf(-0.001f);   // exp(-DT/TAU_FILTER)
    const float dec_r = expf(-0.04f);    // exp(-DT/TAU_REF)

    float hy[16], hz[16], rf[16], vv[16], ft[16], fs[16];
    unsigned long long msk[16];
    #pragma unroll
    for (int s = 0; s < 16; ++s) {
        hy[s]=0.f; hz[s]=0.f; rf[s]=0.f; vv[s]=0.f; ft[s]=0.f; fs[s]=0.f;
        msk[s]=0ull;
    }

    __syncthreads();   // once; block == 1 wave so this is near-free

    const float4* h2h4 = (const float4*)h2h;   // row k: h2h4[k*256 + j*64 + lane]
    float xt = xrow[0];
    unsigned long long anyp = 0ull;

    for (int step = 0; step < LT; ++step) {
        // Prefetch next step's input (hides LDS latency behind the math).
        const float xt_next = xrow[(step + 1) & (LT - 1)];

        // ---- cold path: recurrent gather from previous step's spikes ----
        // anyp is a scalar (ballot-derived) -> uniform branch, never taken for
        // these inputs. Folding a into vv as vv += dt*a is exact in real
        // arithmetic (linearity of the vv update), O(dt^2) rounding delta.
        if (anyp) {
            float a[16];
            #pragma unroll
            for (int s = 0; s < 16; ++s) a[s] = 0.f;
            #pragma unroll
            for (int s = 0; s < 16; ++s) {
                unsigned long long m = msk[s];
                while (m) {
                    const int l = __builtin_ctzll(m);
                    m &= (m - 1);
                    const int k = (s >> 2) * 256 + l * 4 + (s & 3); // spiked unit
                    const size_t rowb = (size_t)k * 256;
                    #pragma unroll
                    for (int jj = 0; jj < 4; ++jj) {
                        const float4 r = h2h4[rowb + jj * 64 + lane];
                        a[jj*4+0] += r.x; a[jj*4+1] += r.y;
                        a[jj*4+2] += r.z; a[jj*4+3] += r.w;
                    }
                }
            }
            #pragma unroll
            for (int s = 0; s < 16; ++s) vv[s] = fmaf(dt, a[s], vv[s]);
        }

        // ---- hot pointwise update: 17 VALU per unit ----
        anyp = 0ull;
        #pragma unroll
        for (int s = 0; s < 16; ++s) {
            const float t0 = fmaf(xt, wx[s], bi[s]);        // I (a folded above)
            const float u  = fmaf(-0.05f, vv[s], t0);       // I - v/TAU_M
            vv[s] = fmaf(dt, u, vv[s]);
            const bool  lc  = vv[s] > 1.0f;                 // LIF spike
            const float sgl = lc ? sg : 0.0f;               // spike_gain * lif_s
            vv[s] = lc ? vv[s] - 1.0f : vv[s];              // subtract theta
            float t1 = fmaf(-g[s], hy[s], sgl);
            t1       = fmaf(-ep[s], hz[s], t1);
            hz[s] = fmaf(dt, t1, hz[s]);
            hy[s] = fmaf(dt, hz[s], hy[s]);                 // uses updated hz
            const bool sc = (hy[s] - rf[s]) > 1.0f;         // RF spike, old ref
            msk[s] = __ballot(sc);
            anyp |= msk[s];
            const float sn = sc ? 1.0f : 0.0f;
            rf[s] = fmaf(dec_r, rf[s], sn);
            ft[s] = fmaf(dec_f, ft[s], sn);
            fs[s] += ft[s];
        }
        xt = xt_next;
    }

    // out[b] = concat(fts/L, ft); coalesced float4 stores.
    const float inv = 1.0f / 1024.0f;   // exact pow2
    float* ob = out + (size_t)b * (2 * NH);
    #pragma unroll
    for (int j = 0; j < 4; ++j) {
        float4 mo = {fs[j*4+0]*inv, fs[j*4+1]*inv, fs[j*4+2]*inv, fs[j*4+3]*inv};
        float4 to = {ft[j*4+0], ft[j*4+1], ft[j*4+2], ft[j*4+3]};
        ((float4*)ob)[j*64 + lane]        = mo;
        ((float4*)(ob + NH))[j*64 + lane] = to;
    }
}

extern "C" void kernel_launch(void* const* d_in, const int* in_sizes, int n_in,
                              void* d_out, int out_size, void* d_ws, size_t ws_size,
                              hipStream_t stream) {
    const float* x     = (const float*)d_in[0];
    const float* x2h   = (const float*)d_in[1];
    const float* h2h   = (const float*)d_in[2];
    const float* bias  = (const float*)d_in[3];
    const float* gam   = (const float*)d_in[4];
    const float* eps   = (const float*)d_in[5];
    const float* sgain = (const float*)d_in[6];
    float* out = (float*)d_out;

    coesn_kernel<<<dim3(2048), dim3(64), 0, stream>>>(
        x, x2h, h2h, bias, gam, eps, sgain, out);
}

// Round 4
// 806.046 us; speedup vs baseline: 2.5623x; 1.0047x over previous
//
#include <hip/hip_runtime.h>

// spiking coESN: B=2048 samples, L=1024 steps, N_HID=1024.
// R4: one wave per sample, 64-thread blocks. Lane owns 16 units as 8 float2
// pairs: unit(j,c) = j*256 + lane*4 + c, pair p -> units (2p, 2p+1).
// Hot loop on float2 ext-vectors -> v_pk_fma_f32 (full-rate 2xf32 on CDNA4):
// 12 packed + 10 scalar ops per pair (~11 issue/unit vs 17 scalar).
// amdgpu_waves_per_eu(2,2): grid gives exactly 2 waves/SIMD, so target that
// occupancy -> 256-VGPR budget, no spill-for-occupancy (R3: VGPR=100 = consts
// spilled to scratch, ~100 extra ops/step).
// Packed FMA is IEEE FMA per component, same expressions/order as R3 (passed,
// absmax 0.0) => bit-identical trajectories.

#define NH 1024
#define LT 1024

typedef float v2f __attribute__((ext_vector_type(2)));

__global__ __launch_bounds__(64) __attribute__((amdgpu_waves_per_eu(2, 2)))
void coesn_kernel(const float* __restrict__ x,      // (B, L, 1)
                  const float* __restrict__ x2h,    // (1, NH)
                  const float* __restrict__ h2h,    // (NH, NH) row-major
                  const float* __restrict__ bias,   // (NH,)
                  const float* __restrict__ gam,    // (NH,)
                  const float* __restrict__ eps,    // (NH,)
                  const float* __restrict__ sgain,  // (1,)
                  float* __restrict__ out)          // (B, 2*NH)
{
    const int lane = threadIdx.x;     // 0..63, one wave per block
    const int b    = blockIdx.x;

    __shared__ float xrow[LT];        // this sample's input series, 4 KB

    // Stage x[b,:,0]: 64 threads x float4 x 4 iters = 1024 floats.
    {
        const float4* src = (const float4*)(x + (size_t)b * LT);
        float4* dst = (float4*)xrow;
        #pragma unroll
        for (int i = 0; i < 4; ++i)
            dst[lane + 64 * i] = src[lane + 64 * i];
    }

    // Per-unit constants as 8 float2 pairs; float4 idx j*64+lane holds
    // pairs 2j (x,y) and 2j+1 (z,w).
    v2f g2[8], ep2[8], bi2[8], wx2[8];
    #pragma unroll
    for (int j = 0; j < 4; ++j) {
        const int fi = j * 64 + lane;
        float4 t4;
        t4 = ((const float4*)gam)[fi];
        g2[2*j]   = v2f{t4.x, t4.y};  g2[2*j+1]  = v2f{t4.z, t4.w};
        t4 = ((const float4*)eps)[fi];
        ep2[2*j]  = v2f{t4.x, t4.y};  ep2[2*j+1] = v2f{t4.z, t4.w};
        t4 = ((const float4*)bias)[fi];
        bi2[2*j]  = v2f{t4.x, t4.y};  bi2[2*j+1] = v2f{t4.z, t4.w};
        t4 = ((const float4*)x2h)[fi];
        wx2[2*j]  = v2f{t4.x, t4.y};  wx2[2*j+1] = v2f{t4.z, t4.w};
    }
    // Pin constants into VGPRs (block remat/sinking into the loop).
    #pragma unroll
    for (int p = 0; p < 8; ++p) {
        asm volatile("" : "+v"(g2[p]), "+v"(ep2[p]), "+v"(bi2[p]), "+v"(wx2[p]));
    }

    const float sg    = sgain[0];
    const v2f   vdt   = {0.01f, 0.01f};
    const float dcf   = expf(-0.001f);   // exp(-DT/TAU_FILTER)
    const float dcr   = expf(-0.04f);    // exp(-DT/TAU_REF)
    const v2f   vdecf = {dcf, dcf};
    const v2f   vdecr = {dcr, dcr};
    const v2f   vntau = {-0.05f, -0.05f};  // -1/LIF_TAU_M
    const v2f   vm1   = {-1.0f, -1.0f};

    v2f hy2[8], hz2[8], rf2[8], vv2[8], ft2[8], fs2[8];
    unsigned long long msk[16];
    #pragma unroll
    for (int p = 0; p < 8; ++p) {
        hy2[p] = v2f{0.f, 0.f}; hz2[p] = v2f{0.f, 0.f}; rf2[p] = v2f{0.f, 0.f};
        vv2[p] = v2f{0.f, 0.f}; ft2[p] = v2f{0.f, 0.f}; fs2[p] = v2f{0.f, 0.f};
    }
    #pragma unroll
    for (int s = 0; s < 16; ++s) msk[s] = 0ull;

    __syncthreads();   // once; block == 1 wave

    const float4* h2h4 = (const float4*)h2h;   // row k: h2h4[k*256 + j*64 + lane]
    float xt = xrow[0];
    unsigned long long anyp = 0ull;

    for (int step = 0; step < LT; ++step) {
        const float xt_next = xrow[(step + 1) & (LT - 1)];  // prefetch

        // ---- cold path: recurrent gather from previous step's spikes ----
        // anyp is ballot-derived (uniform); never taken for these inputs.
        // vv += dt*a fold: exact in real arithmetic, O(dt^2) rounding delta.
        if (anyp) {
            v2f a2[8];
            #pragma unroll
            for (int p = 0; p < 8; ++p) a2[p] = v2f{0.f, 0.f};
            #pragma unroll
            for (int s = 0; s < 16; ++s) {
                unsigned long long m = msk[s];
                while (m) {
                    const int l = __builtin_ctzll(m);
                    m &= (m - 1);
                    const int k = (s >> 2) * 256 + l * 4 + (s & 3); // spiked unit
                    const size_t rowb = (size_t)k * 256;
                    #pragma unroll
                    for (int jj = 0; jj < 4; ++jj) {
                        const float4 r = h2h4[rowb + jj * 64 + lane];
                        a2[2*jj]   += v2f{r.x, r.y};
                        a2[2*jj+1] += v2f{r.z, r.w};
                    }
                }
            }
            #pragma unroll
            for (int p = 0; p < 8; ++p)
                vv2[p] = __builtin_elementwise_fma(vdt, a2[p], vv2[p]);
        }

        // ---- hot pointwise update: 8 pairs, packed FMA + scalar cmp/sel ----
        anyp = 0ull;
        const v2f xt2 = {xt, xt};
        #pragma unroll
        for (int p = 0; p < 8; ++p) {
            v2f t0 = __builtin_elementwise_fma(xt2, wx2[p], bi2[p]);   // I
            v2f u  = __builtin_elementwise_fma(vntau, vv2[p], t0);     // I - v/TAU
            vv2[p] = __builtin_elementwise_fma(vdt, u, vv2[p]);
            const bool lc0 = vv2[p].x > 1.0f;                // LIF spikes
            const bool lc1 = vv2[p].y > 1.0f;
            v2f sgl; sgl.x = lc0 ? sg : 0.0f; sgl.y = lc1 ? sg : 0.0f;
            const v2f vvm = vv2[p] + vm1;                    // packed v-theta
            vv2[p].x = lc0 ? vvm.x : vv2[p].x;
            vv2[p].y = lc1 ? vvm.y : vv2[p].y;
            v2f t1 = __builtin_elementwise_fma(-g2[p], hy2[p], sgl);
            t1     = __builtin_elementwise_fma(-ep2[p], hz2[p], t1);
            hz2[p] = __builtin_elementwise_fma(vdt, t1, hz2[p]);
            hy2[p] = __builtin_elementwise_fma(vdt, hz2[p], hy2[p]);
            const v2f d = hy2[p] - rf2[p];                   // RF margin
            const bool sc0 = d.x > 1.0f;
            const bool sc1 = d.y > 1.0f;
            msk[2*p]   = __ballot(sc0);
            msk[2*p+1] = __ballot(sc1);
            anyp |= msk[2*p] | msk[2*p+1];
            v2f sn; sn.x = sc0 ? 1.0f : 0.0f; sn.y = sc1 ? 1.0f : 0.0f;
            rf2[p] = __builtin_elementwise_fma(vdecr, rf2[p], sn);
            ft2[p] = __builtin_elementwise_fma(vdecf, ft2[p], sn);
            fs2[p] += ft2[p];
        }
        xt = xt_next;
    }

    // out[b] = concat(fts/L, ft); coalesced float4 stores.
    const float inv = 1.0f / 1024.0f;   // exact pow2
    float* ob = out + (size_t)b * (2 * NH);
    #pragma unroll
    for (int j = 0; j < 4; ++j) {
        float4 mo = {fs2[2*j].x * inv, fs2[2*j].y * inv,
                     fs2[2*j+1].x * inv, fs2[2*j+1].y * inv};
        float4 to = {ft2[2*j].x, ft2[2*j].y, ft2[2*j+1].x, ft2[2*j+1].y};
        ((float4*)ob)[j*64 + lane]        = mo;
        ((float4*)(ob + NH))[j*64 + lane] = to;
    }
}

extern "C" void kernel_launch(void* const* d_in, const int* in_sizes, int n_in,
                              void* d_out, int out_size, void* d_ws, size_t ws_size,
                              hipStream_t stream) {
    const float* x     = (const float*)d_in[0];
    const float* x2h   = (const float*)d_in[1];
    const float* h2h   = (const float*)d_in[2];
    const float* bias  = (const float*)d_in[3];
    const float* gam   = (const float*)d_in[4];
    const float* eps   = (const float*)d_in[5];
    const float* sgain = (const float*)d_in[6];
    float* out = (float*)d_out;

    coesn_kernel<<<dim3(2048), dim3(64), 0, stream>>>(
        x, x2h, h2h, bias, gam, eps, sgain, out);
}

// Round 5
// 629.430 us; speedup vs baseline: 3.2812x; 1.2806x over previous
//
#include <hip/hip_runtime.h>

// spiking coESN: B=2048 samples, L=1024 steps, N_HID=1024.
// R5: one wave per sample (64-thr blocks), 16 units/lane.
// FAST/FULL mode split. Fast loop (runs unless an RF spike occurs, which for
// this input never happens - absmax 0.0 across R1-R4) carries only vv/hz/hy
// (48 regs) + dt-folded consts (64 regs): 10 VALU/unit-step, ONE ballot/step
// via max-reduction. rf/ft/fs are provably 0 absent RF spikes -> not computed.
// On first spike (uniform branch): completion + full R3-style loop with
// per-unit masks and sparse h2h gather -> correct for general inputs.
// dt-folded arithmetic differs from reference at O(dt^2); only effect is
// borderline LIF-spike timing, perturbing hy by ~1e-3 vs the 0.95 RF margin.

#define NH 1024
#define LT 1024

__global__ __launch_bounds__(64) __attribute__((amdgpu_waves_per_eu(2, 2)))
void coesn_kernel(const float* __restrict__ x,      // (B, L, 1)
                  const float* __restrict__ x2h,    // (1, NH)
                  const float* __restrict__ h2h,    // (NH, NH) row-major
                  const float* __restrict__ bias,   // (NH,)
                  const float* __restrict__ gam,    // (NH,)
                  const float* __restrict__ eps,    // (NH,)
                  const float* __restrict__ sgain,  // (1,)
                  float* __restrict__ out)          // (B, 2*NH)
{
    const int lane = threadIdx.x;     // 0..63, one wave per block
    const int b    = blockIdx.x;

    __shared__ float xrow[LT + 4];    // +pad so xrow[step+1] is always in-bounds

    // Stage x[b,:,0]: 64 threads x float4 x 4 iters = 1024 floats.
    {
        const float4* src = (const float4*)(x + (size_t)b * LT);
        float4* dst = (float4*)xrow;
        #pragma unroll
        for (int i = 0; i < 4; ++i)
            dst[lane + 64 * i] = src[lane + 64 * i];
        if (lane == 0) xrow[LT] = 0.0f;
    }

    const float dt  = 0.01f;
    const float cv  = 0.9995f;            // 1 - dt/LIF_TAU_M
    const float dcf = expf(-0.001f);      // exp(-DT/TAU_FILTER)
    const float dcr = expf(-0.04f);       // exp(-DT/TAU_REF)
    const float dsg = dt * sgain[0];      // dt * spike_gain

    // dt-folded per-unit constants; unit(j,c) = j*256 + lane*4 + c.
    float dwx[16], dbi[16], dg[16], cez[16];
    #pragma unroll
    for (int j = 0; j < 4; ++j) {
        const int fi = j * 64 + lane;
        float4 t4;
        t4 = ((const float4*)x2h)[fi];
        dwx[j*4+0]=dt*t4.x; dwx[j*4+1]=dt*t4.y; dwx[j*4+2]=dt*t4.z; dwx[j*4+3]=dt*t4.w;
        t4 = ((const float4*)bias)[fi];
        dbi[j*4+0]=dt*t4.x; dbi[j*4+1]=dt*t4.y; dbi[j*4+2]=dt*t4.z; dbi[j*4+3]=dt*t4.w;
        t4 = ((const float4*)gam)[fi];
        dg[j*4+0]=dt*t4.x;  dg[j*4+1]=dt*t4.y;  dg[j*4+2]=dt*t4.z;  dg[j*4+3]=dt*t4.w;
        t4 = ((const float4*)eps)[fi];
        cez[j*4+0]=1.0f-dt*t4.x; cez[j*4+1]=1.0f-dt*t4.y;
        cez[j*4+2]=1.0f-dt*t4.z; cez[j*4+3]=1.0f-dt*t4.w;
    }
    // Keep constants register-resident (block sinking loads into the loop).
    #pragma unroll
    for (int s = 0; s < 16; ++s) {
        asm volatile("" : "+v"(dwx[s]), "+v"(dbi[s]), "+v"(dg[s]), "+v"(cez[s]));
    }

    float vv[16], hz[16], hy[16];
    #pragma unroll
    for (int s = 0; s < 16; ++s) { vv[s]=0.f; hz[s]=0.f; hy[s]=0.f; }

    __syncthreads();   // one wave; near-free

    float xt = xrow[0];
    int step = 0;

    // ---------------- FAST LOOP: no RF spikes so far ----------------
    // rf == ft == fs == 0 invariant; spike condition reduces to hy > 1.
    for (; step < LT; ++step) {
        const float xt_next = xrow[step + 1];
        float mx = -1e30f;
        #pragma unroll
        for (int s = 0; s < 16; ++s) {
            const float t0 = fmaf(xt, dwx[s], dbi[s]);     // dt * I
            vv[s] = fmaf(cv, vv[s], t0);
            const bool lc = vv[s] > 1.0f;                  // LIF spike
            vv[s] = lc ? vv[s] - 1.0f : vv[s];
            const float ks = lc ? dsg : 0.0f;              // dt*sg*lif_s
            const float t1 = fmaf(-dg[s], hy[s], ks);
            hz[s] = fmaf(cez[s], hz[s], t1);
            hy[s] = fmaf(dt, hz[s], hy[s]);
            mx = fmaxf(mx, hy[s]);
        }
        xt = xt_next;
        if (__builtin_expect(__ballot(mx > 1.0f) != 0ull, 0)) break;  // RF spike!
    }

    float rf[16], ft[16], fs[16];
    #pragma unroll
    for (int s = 0; s < 16; ++s) { rf[s]=0.f; ft[s]=0.f; fs[s]=0.f; }

    if (step < LT) {
        // ------------- transition: complete the spiking step -------------
        unsigned long long msk[16];
        unsigned long long anyp = 0ull;
        #pragma unroll
        for (int s = 0; s < 16; ++s) {
            const bool sc = hy[s] > 1.0f;                  // rf was 0
            msk[s] = __ballot(sc);
            anyp |= msk[s];
            const float sn = sc ? 1.0f : 0.0f;
            rf[s] = sn; ft[s] = sn; fs[s] = sn;            // from zero state
        }
        ++step;

        // ---------------- FULL LOOP: masks + sparse gather ----------------
        const float4* h2h4 = (const float4*)h2h;
        for (; step < LT; ++step) {
            const float xt_next = xrow[step + 1];

            if (anyp) {   // uniform; gather prev-step spikes, fold vv += dt*a
                float a[16];
                #pragma unroll
                for (int s = 0; s < 16; ++s) a[s] = 0.f;
                #pragma unroll
                for (int s = 0; s < 16; ++s) {
                    unsigned long long m = msk[s];
                    while (m) {
                        const int l = __builtin_ctzll(m);
                        m &= (m - 1);
                        const int k = (s >> 2) * 256 + l * 4 + (s & 3);
                        const size_t rowb = (size_t)k * 256;
                        #pragma unroll
                        for (int jj = 0; jj < 4; ++jj) {
                            const float4 r = h2h4[rowb + jj * 64 + lane];
                            a[jj*4+0] += r.x; a[jj*4+1] += r.y;
                            a[jj*4+2] += r.z; a[jj*4+3] += r.w;
                        }
                    }
                }
                #pragma unroll
                for (int s = 0; s < 16; ++s) vv[s] = fmaf(dt, a[s], vv[s]);
            }

            anyp = 0ull;
            #pragma unroll
            for (int s = 0; s < 16; ++s) {
                const float t0 = fmaf(xt, dwx[s], dbi[s]);
                vv[s] = fmaf(cv, vv[s], t0);
                const bool lc = vv[s] > 1.0f;
                vv[s] = lc ? vv[s] - 1.0f : vv[s];
                const float ks = lc ? dsg : 0.0f;
                const float t1 = fmaf(-dg[s], hy[s], ks);
                hz[s] = fmaf(cez[s], hz[s], t1);
                hy[s] = fmaf(dt, hz[s], hy[s]);
                const bool sc = (hy[s] - rf[s]) > 1.0f;    // RF spike, old ref
                msk[s] = __ballot(sc);
                anyp |= msk[s];
                const float sn = sc ? 1.0f : 0.0f;
                rf[s] = fmaf(dcr, rf[s], sn);
                ft[s] = fmaf(dcf, ft[s], sn);
                fs[s] += ft[s];
            }
            xt = xt_next;
        }
    }

    // out[b] = concat(fts/L, ft); coalesced float4 stores.
    const float inv = 1.0f / 1024.0f;   // exact pow2
    float* ob = out + (size_t)b * (2 * NH);
    #pragma unroll
    for (int j = 0; j < 4; ++j) {
        float4 mo = {fs[j*4+0]*inv, fs[j*4+1]*inv, fs[j*4+2]*inv, fs[j*4+3]*inv};
        float4 to = {ft[j*4+0], ft[j*4+1], ft[j*4+2], ft[j*4+3]};
        ((float4*)ob)[j*64 + lane]        = mo;
        ((float4*)(ob + NH))[j*64 + lane] = to;
    }
}

extern "C" void kernel_launch(void* const* d_in, const int* in_sizes, int n_in,
                              void* d_out, int out_size, void* d_ws, size_t ws_size,
                              hipStream_t stream) {
    const float* x     = (const float*)d_in[0];
    const float* x2h   = (const float*)d_in[1];
    const float* h2h   = (const float*)d_in[2];
    const float* bias  = (const float*)d_in[3];
    const float* gam   = (const float*)d_in[4];
    const float* eps   = (const float*)d_in[5];
    const float* sgain = (const float*)d_in[6];
    float* out = (float*)d_out;

    coesn_kernel<<<dim3(2048), dim3(64), 0, stream>>>(
        x, x2h, h2h, bias, gam, eps, sgain, out);
}

// Round 6
// 461.292 us; speedup vs baseline: 4.4772x; 1.3645x over previous
//
#include <hip/hip_runtime.h>

// spiking coESN: B=2048 samples, L=1024 steps, N_HID=1024.
// R6: TWO waves per sample (128-thr block), 8 units/lane -> ~70-VGPR working
// set (R2-R5 all pinned at VGPR_Count=100 with a 112-float live set; the ~2x
// VALU-op bloat was spill/remat traffic, incl. AGPR-copy VALU ops).
// FAST phase: each wave integrates its own 512 units for ALL 1024 steps with
// ZERO synchronization (before the sample's first RF spike there is no
// recurrent input and rf=ft=fs=0; each wave's trajectory is exact for its own
// units until then, so the first spike is always detected by its owner).
// One flag-combine barrier at the end. If any spike occurred (never for this
// input: absmax 0.0 in R1-R5): FULL REPLAY from the known zero state with
// per-step LDS mask exchange (1 barrier/step) -> correct for general inputs.
// unit(j,c) = (2w+j)*256 + lane*4 + c, j in {0,1} -> all global accesses are
// coalesced float4.

#define NH 1024
#define LT 1024

__global__ __launch_bounds__(128) __attribute__((amdgpu_waves_per_eu(4, 4)))
void coesn_kernel(const float* __restrict__ x,      // (B, L, 1)
                  const float* __restrict__ x2h,    // (1, NH)
                  const float* __restrict__ h2h,    // (NH, NH) row-major
                  const float* __restrict__ bias,   // (NH,)
                  const float* __restrict__ gam,    // (NH,)
                  const float* __restrict__ eps,    // (NH,)
                  const float* __restrict__ sgain,  // (1,)
                  float* __restrict__ out)          // (B, 2*NH)
{
    const int tid  = threadIdx.x;     // 0..127
    const int lane = tid & 63;
    const int w    = tid >> 6;        // wave 0/1 within the sample
    const int b    = blockIdx.x;

    __shared__ float xrow[LT + 4];                 // input series (+pad)
    __shared__ unsigned long long mskL[2][16];     // [parity][(2w+j)*4+c]
    __shared__ int flag;

    // Stage x[b,:,0]: 128 threads x float4 x 2 = 1024 floats.
    {
        const float4* src = (const float4*)(x + (size_t)b * LT);
        float4* dst = (float4*)xrow;
        dst[tid]       = src[tid];
        dst[tid + 128] = src[tid + 128];
    }
    if (tid == 0) { flag = 0; xrow[LT] = 0.0f; }
    if (tid < 16) mskL[0][tid] = 0ull;

    const float dt  = 0.01f;
    const float cv  = 0.9995f;            // 1 - dt/LIF_TAU_M
    const float dcf = expf(-0.001f);      // exp(-DT/TAU_FILTER)
    const float dcr = expf(-0.04f);       // exp(-DT/TAU_REF)
    const float dsg = dt * sgain[0];      // dt * spike_gain

    // dt-folded per-unit constants; float4 index fi = (2w+j)*64 + lane.
    float dwx[8], dbi[8], dg[8], cez[8];
    #pragma unroll
    for (int j = 0; j < 2; ++j) {
        const int fi = (2 * w + j) * 64 + lane;
        float4 t4;
        t4 = ((const float4*)x2h)[fi];
        dwx[4*j+0]=dt*t4.x; dwx[4*j+1]=dt*t4.y; dwx[4*j+2]=dt*t4.z; dwx[4*j+3]=dt*t4.w;
        t4 = ((const float4*)bias)[fi];
        dbi[4*j+0]=dt*t4.x; dbi[4*j+1]=dt*t4.y; dbi[4*j+2]=dt*t4.z; dbi[4*j+3]=dt*t4.w;
        t4 = ((const float4*)gam)[fi];
        dg[4*j+0]=dt*t4.x;  dg[4*j+1]=dt*t4.y;  dg[4*j+2]=dt*t4.z;  dg[4*j+3]=dt*t4.w;
        t4 = ((const float4*)eps)[fi];
        cez[4*j+0]=1.0f-dt*t4.x; cez[4*j+1]=1.0f-dt*t4.y;
        cez[4*j+2]=1.0f-dt*t4.z; cez[4*j+3]=1.0f-dt*t4.w;
    }

    float vv[8], hz[8], hy[8];
    #pragma unroll
    for (int s = 0; s < 8; ++s) { vv[s]=0.f; hz[s]=0.f; hy[s]=0.f; }

    __syncthreads();

    // ---------------- FAST PHASE: no sync, no masks, no rf/ft/fs ----------
    float xt  = xrow[0];
    float mx0 = -1.0f, mx1 = -1.0f;      // two running-max accumulators (ILP)
    for (int step = 0; step < LT; ++step) {
        const float xt_next = xrow[step + 1];
        #pragma unroll
        for (int s = 0; s < 8; ++s) {
            const float t0 = fmaf(xt, dwx[s], dbi[s]);     // dt * I
            vv[s] = fmaf(cv, vv[s], t0);
            const bool lc = vv[s] > 1.0f;                  // LIF spike
            vv[s] = lc ? vv[s] - 1.0f : vv[s];
            const float ks = lc ? dsg : 0.0f;              // dt*sg*lif_s
            const float t1 = fmaf(-dg[s], hy[s], ks);
            hz[s] = fmaf(cez[s], hz[s], t1);
            hy[s] = fmaf(dt, hz[s], hy[s]);
            if (s & 1) mx1 = fmaxf(mx1, hy[s]); else mx0 = fmaxf(mx0, hy[s]);
        }
        xt = xt_next;
    }
    // RF-spike detection: exact up to the sample's first spike (rf==0 there).
    if (__ballot(fmaxf(mx0, mx1) > 1.0f) != 0ull) {
        if (lane == 0) flag = 1;         // both waves may write 1: benign
    }
    __syncthreads();
    const bool spiked = (flag != 0);

    float* ob = out + (size_t)b * (2 * NH);

    if (!spiked) {
        // rf/ft/fs provably zero -> output is zeros.
        const float4 z = {0.f, 0.f, 0.f, 0.f};
        #pragma unroll
        for (int j = 0; j < 2; ++j) {
            ((float4*)ob)[(2*w+j)*64 + lane]        = z;
            ((float4*)(ob + NH))[(2*w+j)*64 + lane] = z;
        }
        return;
    }

    // ---------------- COLD: full replay from zero state --------------------
    // Per-step: gather prev-step spikes (16 uniform masks from LDS), pointwise
    // update with rf/ft/fs, publish this step's 8 masks, 1 barrier (dbuf).
    {
        float rf[8], ft[8], fs[8];
        #pragma unroll
        for (int s = 0; s < 8; ++s) {
            vv[s]=0.f; hz[s]=0.f; hy[s]=0.f; rf[s]=0.f; ft[s]=0.f; fs[s]=0.f;
        }
        const float4* h2h4 = (const float4*)h2h;
        float xc = xrow[0];

        for (int step = 0; step < LT; ++step) {
            const int p = step & 1;
            const float xc_next = xrow[step + 1];

            float a[8];
            #pragma unroll
            for (int s = 0; s < 8; ++s) a[s] = 0.f;
            // Fixed unit order: q = (2w'+j')*4 + c ascending, lane ascending.
            #pragma unroll
            for (int q = 0; q < 16; ++q) {
                unsigned long long m = mskL[p][q];
                const int wj = q >> 2;   // (2w'+j') in 0..3
                const int c  = q & 3;
                while (m) {
                    const int l = __builtin_ctzll(m);
                    m &= (m - 1);
                    const int k = wj * 256 + l * 4 + c;     // spiked unit
                    const size_t rowb = (size_t)k * 256;
                    #pragma unroll
                    for (int j = 0; j < 2; ++j) {
                        const float4 r = h2h4[rowb + (2*w+j)*64 + lane];
                        a[4*j+0] += r.x; a[4*j+1] += r.y;
                        a[4*j+2] += r.z; a[4*j+3] += r.w;
                    }
                }
            }

            #pragma unroll
            for (int s = 0; s < 8; ++s) {
                float t0 = fmaf(xc, dwx[s], dbi[s]);       // dt*(xt*wx + bias)
                t0 = fmaf(dt, a[s], t0);                   // + dt * (s@h2h)
                vv[s] = fmaf(cv, vv[s], t0);
                const bool lc = vv[s] > 1.0f;
                vv[s] = lc ? vv[s] - 1.0f : vv[s];
                const float ks = lc ? dsg : 0.0f;
                const float t1 = fmaf(-dg[s], hy[s], ks);
                hz[s] = fmaf(cez[s], hz[s], t1);
                hy[s] = fmaf(dt, hz[s], hy[s]);
                const bool sc = (hy[s] - rf[s]) > 1.0f;    // RF spike, old ref
                const unsigned long long mm = __ballot(sc);
                if (lane == 0)
                    mskL[p ^ 1][(2*w + (s >> 2)) * 4 + (s & 3)] = mm;
                const float sn = sc ? 1.0f : 0.0f;
                rf[s] = fmaf(dcr, rf[s], sn);
                ft[s] = fmaf(dcf, ft[s], sn);
                fs[s] += ft[s];
            }
            xc = xc_next;
            __syncthreads();   // masks visible; prev buffer free for reuse
        }

        const float inv = 1.0f / 1024.0f;
        #pragma unroll
        for (int j = 0; j < 2; ++j) {
            float4 mo = {fs[4*j+0]*inv, fs[4*j+1]*inv, fs[4*j+2]*inv, fs[4*j+3]*inv};
            float4 to = {ft[4*j+0], ft[4*j+1], ft[4*j+2], ft[4*j+3]};
            ((float4*)ob)[(2*w+j)*64 + lane]        = mo;
            ((float4*)(ob + NH))[(2*w+j)*64 + lane] = to;
        }
    }
}

extern "C" void kernel_launch(void* const* d_in, const int* in_sizes, int n_in,
                              void* d_out, int out_size, void* d_ws, size_t ws_size,
                              hipStream_t stream) {
    const float* x     = (const float*)d_in[0];
    const float* x2h   = (const float*)d_in[1];
    const float* h2h   = (const float*)d_in[2];
    const float* bias  = (const float*)d_in[3];
    const float* gam   = (const float*)d_in[4];
    const float* eps   = (const float*)d_in[5];
    const float* sgain = (const float*)d_in[6];
    float* out = (float*)d_out;

    coesn_kernel<<<dim3(2048), dim3(128), 0, stream>>>(
        x, x2h, h2h, bias, gam, eps, sgain, out);
}